// Round 6
// baseline (1490.624 us; speedup 1.0000x reference)
//
#include <hip/hip_runtime.h>

#define NF 64
#define NH 32
#define NK 16
#define BLOCK 512
#define NWAVES (BLOCK / 64)

// Structure: R4's per-lane compute + in-block counting sort by loc, but NO
// weight staging in LDS. After the sort, weight addresses are wave-uniform ->
// a float4 load is ONE L1 transaction broadcast to 64 lanes (TA dedup), same
// as R4's W1 path. Dropping W2L: LDS 65 KB -> 2.3 KB, occupancy 2 -> ~5
// waves/SIMD (R4's 65% idle was 1 block/CU with nothing to hide latency).
// R5's SGPR-waterfall is rejected: 1024-float W2 can't live in ~96 SGPRs.

__global__ __attribute__((amdgpu_flat_work_group_size(BLOCK, BLOCK),
                          amdgpu_waves_per_eu(4, 8)))
void tree_mlp_kernel(
    const float* __restrict__ x,
    const float* __restrict__ W1, const float* __restrict__ b1,
    const float* __restrict__ W2, const float* __restrict__ b2,
    const float* __restrict__ W3, const float* __restrict__ b3,
    const float* __restrict__ leaf_best, const int* __restrict__ subset_idx,
    float* __restrict__ out, int N)
{
    __shared__ unsigned permL[BLOCK];   // 2048 B
    __shared__ int      sortL[64];      // 256 B  (nb*NWAVES <= 64)

    const int tid  = threadIdx.x;
    const int lane = tid & 63;
    const int wv   = tid >> 6;

    const int s = blockIdx.x * BLOCK + tid;
    int valid = (s < N) ? 1 : 0;
    int id    = valid ? s : 0;          // invalid lanes shadow sample 0, stay live
    int loc = 0, off = 0;

    #pragma unroll 1                    // keep level loop rolled (I$); body ~1.6k FMAs
    for (int level = 0; level < 4; ++level) {
        if (level > 0) {
            // ---- in-block counting sort by loc (ballot-based) ----
            const int nb = 1 << level;
            int myrank = 0;
            #pragma unroll 1
            for (int b = 0; b < nb; ++b) {
                const unsigned long long m = __ballot(loc == b);
                if (loc == b)
                    myrank = __popcll(m & ((1ull << lane) - 1ull));
                if (lane == 0)
                    sortL[b * NWAVES + wv] = (int)__popcll(m);
            }
            __syncthreads();
            // wave-parallel exclusive prefix over (bucket, wave) — replaces
            // R4's serial tid==0 loop (112 dependent LDS round-trips/level)
            if (wv == 0) {
                const int mcnt = nb * NWAVES;
                const int cnt = (lane < mcnt) ? sortL[lane] : 0;
                int v = cnt;
                #pragma unroll
                for (int d = 1; d < 64; d <<= 1) {
                    const int t = __shfl_up(v, d);
                    if (lane >= d) v += t;
                }
                if (lane < mcnt) sortL[lane] = v - cnt;
            }
            __syncthreads();
            const int slot = sortL[loc * NWAVES + wv] + myrank;
            permL[slot] = ((unsigned)id << 5) | ((unsigned)valid << 4) | (unsigned)loc;
            __syncthreads();
            const unsigned p = permL[tid];
            id    = (int)(p >> 5);
            valid = (int)((p >> 4) & 1u);
            loc   = (int)(p & 15u);
            // no extra barrier: next LDS writes are >=1 barrier away (sort of next level)
        }

        const int node = off + loc;     // wave-uniform after sort (boundary waves <=2 nodes)
        const float* xr = x + (size_t)id * NF;

        // Gather 16 subset features (the only scattered loads in the kernel)
        float xs[NK];
        const int* si = subset_idx + node * NK;
        #pragma unroll
        for (int k = 0; k < NK; ++k) xs[k] = xr[si[k]];

        // h1 = leaky(W1[node] @ xs + b1)   (32x16 GEMV, uniform-address float4)
        float h1v[NH];
        const float4* w1g = (const float4*)(W1 + node * (NH * NK));
        const float* b1g = b1 + node * NH;
        #pragma unroll
        for (int j = 0; j < NH; ++j) {
            float acc = b1g[j];
            #pragma unroll
            for (int q = 0; q < NK / 4; ++q) {
                const float4 t = w1g[j * 4 + q];
                acc += t.x * xs[q * 4 + 0];
                acc += t.y * xs[q * 4 + 1];
                acc += t.z * xs[q * 4 + 2];
                acc += t.w * xs[q * 4 + 3];
            }
            h1v[j] = (acc >= 0.f) ? acc : 0.01f * acc;
        }

        // h2 = leaky(W2[node] @ h1 + b2)   (32x32 GEMV, uniform-address float4)
        float h2v[NH];
        const float4* w2g = (const float4*)(W2 + node * (NH * NH));
        const float* b2g = b2 + node * NH;
        #pragma unroll
        for (int g = 0; g < NH; ++g) {
            float acc = b2g[g];
            #pragma unroll
            for (int q = 0; q < NH / 4; ++q) {
                const float4 t = w2g[g * 8 + q];
                acc += t.x * h1v[q * 4 + 0];
                acc += t.y * h1v[q * 4 + 1];
                acc += t.z * h1v[q * 4 + 2];
                acc += t.w * h1v[q * 4 + 3];
            }
            h2v[g] = (acc >= 0.f) ? acc : 0.01f * acc;
        }

        // logits; p0 < 0.5  <=>  l0 < l1  (softmax is monotone)
        const float4* w3g = (const float4*)(W3 + node * 2 * NH);
        float l0 = b3[node * 2 + 0];
        float l1 = b3[node * 2 + 1];
        #pragma unroll
        for (int q = 0; q < NH / 4; ++q) {
            const float4 t0 = w3g[q];
            l0 += t0.x * h2v[q * 4 + 0];
            l0 += t0.y * h2v[q * 4 + 1];
            l0 += t0.z * h2v[q * 4 + 2];
            l0 += t0.w * h2v[q * 4 + 3];
        }
        #pragma unroll
        for (int q = 0; q < NH / 4; ++q) {
            const float4 t1 = w3g[8 + q];
            l1 += t1.x * h2v[q * 4 + 0];
            l1 += t1.y * h2v[q * 4 + 1];
            l1 += t1.z * h2v[q * 4 + 2];
            l1 += t1.w * h2v[q * 4 + 3];
        }

        const int bit = (l0 < l1) ? 1 : 0;
        loc = 2 * loc + bit;
        off = 2 * off + 1;              // node offsets: 0, 1, 3, 7
    }

    if (valid) out[id] = leaf_best[loc];
}

extern "C" void kernel_launch(void* const* d_in, const int* in_sizes, int n_in,
                              void* d_out, int out_size, void* d_ws, size_t ws_size,
                              hipStream_t stream) {
    const float* x         = (const float*)d_in[0];
    const float* W1        = (const float*)d_in[1];
    const float* b1        = (const float*)d_in[2];
    const float* W2        = (const float*)d_in[3];
    const float* b2        = (const float*)d_in[4];
    const float* W3        = (const float*)d_in[5];
    const float* b3        = (const float*)d_in[6];
    const float* leaf_best = (const float*)d_in[7];
    const int*   subset    = (const int*)d_in[8];

    const int N = in_sizes[0] / NF;
    const int grid = (N + BLOCK - 1) / BLOCK;
    tree_mlp_kernel<<<grid, BLOCK, 0, stream>>>(
        x, W1, b1, W2, b2, W3, b3, leaf_best, subset, (float*)d_out, N);
}